// Round 15
// baseline (1977.178 us; speedup 1.0000x reference)
//
#include <hip/hip_runtime.h>
#include <hip/hip_bf16.h>

#define U_N 100000
#define V_N 50000
#define A_N 5000
#define FCS 16384   // edges per fill work-chunk

typedef float4 f4;
typedef unsigned int u32;
typedef __attribute__((ext_vector_type(8))) short bf16x8;
typedef __attribute__((ext_vector_type(4))) float f32x4;

__device__ inline float bflo(u32 p) { return __uint_as_float(p << 16); }
__device__ inline float bfhi(u32 p) { return __uint_as_float(p & 0xffff0000u); }
__device__ inline u32 f2bf(float f) {
  u32 u = __float_as_uint(f);
  return (u + 0x7fffu + ((u >> 16) & 1u)) >> 16;   // RTNE
}
__device__ inline u32 pack2(float lo, float hi) {
  return f2bf(lo) | (f2bf(hi) << 16);
}
__device__ inline bf16x8 ld8(const u32* p) {
  uint4 u = *(const uint4*)p;
  return __builtin_bit_cast(bf16x8, u);
}

__device__ __forceinline__ u32 xcc_id() {
  u32 x;
  asm volatile("s_getreg_b32 %0, hwreg(HW_REG_XCC_ID)" : "=s"(x));
  return x & 7;
}

// acc(fp32) = curH(bf16) = concat(a[na,64], b[nb,64])
__global__ void k_concat2b(const float* __restrict__ a, int na,
                           const float* __restrict__ b, int nb,
                           u32* __restrict__ curH, float* __restrict__ acc) {
  int total4 = (na + nb) * 16;
  for (int i = blockIdx.x * blockDim.x + threadIdx.x; i < total4;
       i += gridDim.x * blockDim.x) {
    int fi = i * 4;
    f4 v = (fi < na * 64) ? *(const f4*)(a + fi)
                          : *(const f4*)(b + (fi - na * 64));
    *(f4*)(acc + fi) = v;
    uint2 h; h.x = pack2(v.x, v.y); h.y = pack2(v.z, v.w);
    *(uint2*)(curH + (fi >> 1)) = h;
  }
}

// ---------------- CSR build ----------------
// count: single pass, quad-vectorized stream read (cnt <= 600KB, L2-resident)
__global__ void k_count(const int* __restrict__ rows, int nnz, int* __restrict__ cnt) {
  int nq = nnz >> 2;
  int tid = blockIdx.x * blockDim.x + threadIdx.x;
  int stride = gridDim.x * blockDim.x;
  for (int q = tid; q < nq; q += stride) {
    int4 r4 = *(const int4*)(rows + q * 4);
    atomicAdd(&cnt[r4.x], 1);
    atomicAdd(&cnt[r4.y], 1);
    atomicAdd(&cnt[r4.z], 1);
    atomicAdd(&cnt[r4.w], 1);
  }
  for (int i = nq * 4 + tid; i < nnz; i += stride)
    atomicAdd(&cnt[rows[i]], 1);
}

__global__ void k_bsum(const int* __restrict__ cnt, int n, int* __restrict__ bsum) {
  __shared__ int red[1024];
  int t = threadIdx.x;
  int i = blockIdx.x * 1024 + t;
  red[t] = (i < n) ? cnt[i] : 0;
  __syncthreads();
  for (int off = 512; off; off >>= 1) {
    if (t < off) red[t] += red[t + off];
    __syncthreads();
  }
  if (t == 0) bsum[blockIdx.x] = red[0];
}

__global__ void k_bscan(int* __restrict__ bsum, int nb) {
  if (threadIdx.x == 0) {
    int run = 0;
    for (int i = 0; i < nb; ++i) {
      int c = bsum[i];
      bsum[i] = run;
      run += c;
    }
  }
}

__global__ void k_bapply(const int* __restrict__ cnt, int n,
                         const int* __restrict__ bsum,
                         int* __restrict__ rp, int* __restrict__ pos) {
  __shared__ int sc[1024];
  int t = threadIdx.x;
  int i = blockIdx.x * 1024 + t;
  int c = (i < n) ? cnt[i] : 0;
  sc[t] = c;
  __syncthreads();
  #pragma unroll
  for (int off = 1; off < 1024; off <<= 1) {
    int v = (t >= off) ? sc[t - off] : 0;
    __syncthreads();
    sc[t] += v;
    __syncthreads();
  }
  int val = bsum[blockIdx.x] + sc[t] - c;   // exclusive
  if (i < n) {
    rp[i] = val;
    pos[i] = val;
    if (i == n - 1) rp[n] = val + c;
  }
}

// XCD-queue windowed fill: window w owned by XCD w%8 (real XCC_ID), so each
// pos/ep line is written by exactly ONE XCD's L2 (kills 8x writeback
// amplification seen r12/r14: WRITE_SIZE 249MB for 32MB of ep).
// Coverage guaranteed by 8-pass work-stealing (correctness never depends on
// block->XCD placement; stealing merely reverts to cross-XCD behavior).
__global__ void k_fillq(const int* __restrict__ rows, const int* __restrict__ cols,
                        const float* __restrict__ vals, int nnz,
                        int* __restrict__ pos, int2* __restrict__ ep,
                        int nrows, int win, int* __restrict__ xq) {
  int nw = (nrows + win - 1) / win;
  int nchunk = (nnz + FCS - 1) / FCS;
  u32 xcd = xcc_id();
  __shared__ int sitem;
  for (int pass = 0; pass < 8; ++pass) {
    int q = ((int)xcd + pass) & 7;
    int nwq = (nw > q) ? ((nw - 1 - q) >> 3) + 1 : 0;   // windows with w%8==q
    int items = nwq * nchunk;
    if (items == 0) continue;
    for (;;) {
      __syncthreads();
      if (threadIdx.x == 0) sitem = atomicAdd(&xq[q], 1);
      __syncthreads();
      int item = sitem;
      if (item >= items) break;
      int wi = item / nchunk;
      int chunk = item - wi * nchunk;
      int w = q + (wi << 3);
      int r0 = w * win, r1 = min(r0 + win, nrows);
      int e0 = chunk * FCS, e1 = min(e0 + FCS, nnz);
      for (int i = e0 + threadIdx.x; i < e1; i += blockDim.x) {
        int r = rows[i];
        if (r >= r0 && r < r1) {
          int slot = atomicAdd(&pos[r], 1);
          ep[slot] = make_int2(cols[i], __float_as_int(vals[i]));
        }
      }
    }
  }
}

// simple one-pass fill (small graphs, window naturally L2-resident)
__global__ void k_fill(const int* __restrict__ rows, const int* __restrict__ cols,
                       const float* __restrict__ vals, int nnz,
                       int* __restrict__ pos, int2* __restrict__ ep) {
  for (int i = blockIdx.x * blockDim.x + threadIdx.x; i < nnz;
       i += gridDim.x * blockDim.x) {
    int slot = atomicAdd(&pos[rows[i]], 1);
    ep[slot] = make_int2(cols[i], __float_as_int(vals[i]));
  }
}

// dedupe batch users -> rlist/rcount (flag must be zeroed)
__global__ void k_mark(const int* __restrict__ users, int nb,
                       int* __restrict__ flag, int* __restrict__ rcount,
                       int* __restrict__ rlist) {
  int b = blockIdx.x * blockDim.x + threadIdx.x;
  if (b < nb) {
    int u = users[b];
    if (atomicExch(&flag[u], 1) == 0) {
      int m = atomicAdd(rcount, 1);
      rlist[m] = u;
    }
  }
}

// ---------------- bf16 gather SpMM row routine ----------------
__device__ __forceinline__ void spmm_row(
    int row, const int* __restrict__ rp, const int2* __restrict__ ep,
    const u32* __restrict__ inH, int instrU,
    u32* __restrict__ outH, int ostrU, int ocolU,
    float* __restrict__ acc, int l2n, int wout, int lane, int eg, int du) {
  int e0 = rp[row], e1 = rp[row + 1];
  float s[8] = {0.f, 0.f, 0.f, 0.f, 0.f, 0.f, 0.f, 0.f};
  int e = e0 + eg;
  for (; e + 8 < e1; e += 16) {
    int2 ed0 = ep[e];
    int2 ed1 = ep[e + 8];
    float v0 = __int_as_float(ed0.y), v1 = __int_as_float(ed1.y);
    uint4 x0 = *(const uint4*)(inH + (size_t)ed0.x * instrU + du);
    uint4 x1 = *(const uint4*)(inH + (size_t)ed1.x * instrU + du);
    s[0] = fmaf(v0, bflo(x0.x), s[0]); s[1] = fmaf(v0, bfhi(x0.x), s[1]);
    s[2] = fmaf(v0, bflo(x0.y), s[2]); s[3] = fmaf(v0, bfhi(x0.y), s[3]);
    s[4] = fmaf(v0, bflo(x0.z), s[4]); s[5] = fmaf(v0, bfhi(x0.z), s[5]);
    s[6] = fmaf(v0, bflo(x0.w), s[6]); s[7] = fmaf(v0, bfhi(x0.w), s[7]);
    s[0] = fmaf(v1, bflo(x1.x), s[0]); s[1] = fmaf(v1, bfhi(x1.x), s[1]);
    s[2] = fmaf(v1, bflo(x1.y), s[2]); s[3] = fmaf(v1, bfhi(x1.y), s[3]);
    s[4] = fmaf(v1, bflo(x1.z), s[4]); s[5] = fmaf(v1, bfhi(x1.z), s[5]);
    s[6] = fmaf(v1, bflo(x1.w), s[6]); s[7] = fmaf(v1, bfhi(x1.w), s[7]);
  }
  if (e < e1) {
    int2 ed0 = ep[e];
    float v0 = __int_as_float(ed0.y);
    uint4 x0 = *(const uint4*)(inH + (size_t)ed0.x * instrU + du);
    s[0] = fmaf(v0, bflo(x0.x), s[0]); s[1] = fmaf(v0, bfhi(x0.x), s[1]);
    s[2] = fmaf(v0, bflo(x0.y), s[2]); s[3] = fmaf(v0, bfhi(x0.y), s[3]);
    s[4] = fmaf(v0, bflo(x0.z), s[4]); s[5] = fmaf(v0, bfhi(x0.z), s[5]);
    s[6] = fmaf(v0, bflo(x0.w), s[6]); s[7] = fmaf(v0, bfhi(x0.w), s[7]);
  }
  #pragma unroll
  for (int j = 0; j < 8; ++j) {
    s[j] += __shfl_xor(s[j], 8);
    s[j] += __shfl_xor(s[j], 16);
    s[j] += __shfl_xor(s[j], 32);
  }
  if (l2n) {
    float ss = 0.f;
    #pragma unroll
    for (int j = 0; j < 8; ++j) ss = fmaf(s[j], s[j], ss);
    ss += __shfl_xor(ss, 1);
    ss += __shfl_xor(ss, 2);
    ss += __shfl_xor(ss, 4);
    float inv = 1.0f / fmaxf(sqrtf(ss), 1e-12f);
    #pragma unroll
    for (int j = 0; j < 8; ++j) s[j] *= inv;
  }
  if (eg == 0) {
    if (wout) {
      uint4 o;
      o.x = pack2(s[0], s[1]); o.y = pack2(s[2], s[3]);
      o.z = pack2(s[4], s[5]); o.w = pack2(s[6], s[7]);
      *(uint4*)(outH + (size_t)row * ostrU + ocolU + du) = o;
    }
    if (acc) {
      float* ap = acc + (size_t)row * 64 + (lane & 7) * 8;
      f4 a0 = *(f4*)ap, a1 = *(f4*)(ap + 4);
      a0.x += s[0]; a0.y += s[1]; a0.z += s[2]; a0.w += s[3];
      a1.x += s[4]; a1.y += s[5]; a1.z += s[6]; a1.w += s[7];
      *(f4*)ap = a0; *(f4*)(ap + 4) = a1;
    }
  }
}

__global__ void k_spmm_b(const int* __restrict__ rp, const int2* __restrict__ ep,
                         int nrows, int rbase,
                         const u32* __restrict__ inH, int instrU,
                         u32* __restrict__ outH, int ostrU, int ocolU,
                         float* __restrict__ acc, int l2n, int wout) {
  int lane = threadIdx.x & 63;
  int w = (blockIdx.x * blockDim.x + threadIdx.x) >> 6;
  int nw = (gridDim.x * blockDim.x) >> 6;
  int eg = lane >> 3;
  int du = (lane & 7) * 4;
  for (int r = w; r < nrows; r += nw)
    spmm_row(rbase + r, rp, ep, inH, instrU, outH, ostrU, ocolU, acc, l2n, wout,
             lane, eg, du);
}

// acc-only SpMM over an explicit row list (deduped)
__global__ void k_spmm_b_list(const int* __restrict__ rp, const int2* __restrict__ ep,
                              const int* __restrict__ rlist, const int* __restrict__ rcount,
                              const u32* __restrict__ inH, int instrU,
                              float* __restrict__ acc) {
  int lane = threadIdx.x & 63;
  int w = (blockIdx.x * blockDim.x + threadIdx.x) >> 6;
  int nw = (gridDim.x * blockDim.x) >> 6;
  int eg = lane >> 3;
  int du = (lane & 7) * 4;
  int m = *rcount;
  for (int r = w; r < m; r += nw)
    spmm_row(rlist[r], rp, ep, inH, instrU, nullptr, 0, 0, acc, 0, 0,
             lane, eg, du);
}

// accUA *= 0.25 in place; user rows also emitted bf16 to UAuH
__global__ void k_scale_ua(float* __restrict__ acc, u32* __restrict__ UAuH) {
  int total4 = (U_N + A_N) * 16;
  for (int i = blockIdx.x * blockDim.x + threadIdx.x; i < total4;
       i += gridDim.x * blockDim.x) {
    int fi = i * 4;
    f4 v = *(f4*)(acc + fi);
    v.x *= 0.25f; v.y *= 0.25f; v.z *= 0.25f; v.w *= 0.25f;
    *(f4*)(acc + fi) = v;
    if (fi < U_N * 64) {
      uint2 h; h.x = pack2(v.x, v.y); h.y = pack2(v.z, v.w);
      *(uint2*)(UAuH + (fi >> 1)) = h;
    }
  }
}

// accUI *= 0.25 in place; video rows emitted bf16 to VAH[:, :64] (stride 64 uints)
__global__ void k_scale_ui(float* __restrict__ acc, u32* __restrict__ VAH) {
  int total4 = (U_N + V_N) * 16;
  for (int i = blockIdx.x * blockDim.x + threadIdx.x; i < total4;
       i += gridDim.x * blockDim.x) {
    int fi = i * 4;
    f4 v = *(f4*)(acc + fi);
    v.x *= 0.25f; v.y *= 0.25f; v.z *= 0.25f; v.w *= 0.25f;
    *(f4*)(acc + fi) = v;
    if (fi >= U_N * 64) {
      int rem = fi - U_N * 64;
      int row = rem >> 6, col = rem & 63;
      uint2 h; h.x = pack2(v.x, v.y); h.y = pack2(v.z, v.w);
      *(uint2*)(VAH + (size_t)row * 64 + (col >> 1)) = h;
    }
  }
}

// UcatH[b] = bf16([atom_u[users[b]] | non_u[users[b]]]); 32 threads/block
__global__ void k_gather_u(const int* __restrict__ users,
                           const float* __restrict__ accUI,
                           const float* __restrict__ accUA,
                           u32* __restrict__ UcatH) {
  int b = blockIdx.x;
  int t = threadIdx.x;
  int u = users[b];
  UcatH[b * 64 + t] = pack2(accUI[(size_t)u * 64 + 2 * t], accUI[(size_t)u * 64 + 2 * t + 1]);
  UcatH[b * 64 + 32 + t] = pack2(accUA[(size_t)u * 64 + 2 * t], accUA[(size_t)u * 64 + 2 * t + 1]);
}

// VBH[v] = [atomAH[vl[v]] | bf16(non_a[vl[v]])]; 128 threads = 4 videos
__global__ void k_gather_vb(const int* __restrict__ vlist,
                            const u32* __restrict__ atomAH,
                            const float* __restrict__ accUA,
                            u32* __restrict__ VBH) {
  int v = blockIdx.x * 4 + (threadIdx.x >> 5);
  int t = threadIdx.x & 31;
  int a = vlist[v];
  VBH[(size_t)v * 64 + t] = atomAH[(size_t)a * 32 + t];
  VBH[(size_t)v * 64 + 32 + t] =
      pack2(accUA[(size_t)(U_N + a) * 64 + 2 * t], accUA[(size_t)(U_N + a) * 64 + 2 * t + 1]);
}

// w[v] = sigmoid( dot( ((atom_v+non_v)/2) @ q , (vl_a+vl_n)/2 ) )
__global__ void k_w(const u32* __restrict__ VAH, const u32* __restrict__ VBH,
                    const float* __restrict__ q, float* __restrict__ wv) {
  __shared__ float qs[64 * 64];
  for (int i = threadIdx.x; i < 4096; i += blockDim.x) qs[i] = q[i];
  __syncthreads();
  int lane = threadIdx.x & 63;
  int v = blockIdx.x * 4 + (threadIdx.x >> 6);
  if (v >= V_N) return;
  int half = lane & 1;
  u32 pa0 = VAH[(size_t)v * 64 + (lane >> 1)];
  u32 pa1 = VAH[(size_t)v * 64 + 32 + (lane >> 1)];
  u32 pb0 = VBH[(size_t)v * 64 + (lane >> 1)];
  u32 pb1 = VBH[(size_t)v * 64 + 32 + (lane >> 1)];
  float vid = 0.5f * ((half ? bfhi(pa0) : bflo(pa0)) + (half ? bfhi(pa1) : bflo(pa1)));
  float vlog = 0.5f * ((half ? bfhi(pb0) : bflo(pb0)) + (half ? bfhi(pb1) : bflo(pb1)));
  float s = 0.0f;
  for (int d = 0; d < 64; ++d)
    s = fmaf(__shfl(vid, d, 64), qs[d * 64 + lane], s);
  float t = s * vlog;
  #pragma unroll
  for (int off = 32; off; off >>= 1) t += __shfl_xor(t, off, 64);
  if (lane == 0) wv[v] = 1.0f / (1.0f + __expf(-t));
}

// MFMA rating v2: block = 4 waves, each wave 32u x 64v; VA/VB tile in LDS.
#define SPAD 68
__global__ __launch_bounds__(256) void k_rating_mfma(
    const u32* __restrict__ UcatH, const u32* __restrict__ VAH,
    const u32* __restrict__ VBH, const float* __restrict__ wv,
    float* __restrict__ out) {
  __shared__ u32 sVA[64 * SPAD];
  __shared__ u32 sVB[64 * SPAD];
  int t = threadIdx.x;
  int n0 = blockIdx.x * 64;
  for (int i = t; i < 1024; i += 256) {
    int row = i >> 4, c4 = (i & 15) * 4;
    int v = n0 + row;
    uint4 a = make_uint4(0, 0, 0, 0), b = make_uint4(0, 0, 0, 0);
    if (v < V_N) {
      a = *(const uint4*)(VAH + (size_t)v * 64 + c4);
      b = *(const uint4*)(VBH + (size_t)v * 64 + c4);
    }
    *(uint4*)(&sVA[row * SPAD + c4]) = a;
    *(uint4*)(&sVB[row * SPAD + c4]) = b;
  }
  __syncthreads();
  int lane = t & 63, wave = t >> 6;
  int m0 = (blockIdx.y * 4 + wave) * 32;
  int rr = lane & 15, g = lane >> 4;
  f32x4 accA[2][4], accB[2][4];
  #pragma unroll
  for (int i = 0; i < 2; ++i)
    #pragma unroll
    for (int j = 0; j < 4; ++j) {
      accA[i][j] = (f32x4){0.f, 0.f, 0.f, 0.f};
      accB[i][j] = (f32x4){0.f, 0.f, 0.f, 0.f};
    }
  const u32* uc0 = UcatH + (size_t)(m0 + rr) * 64 + g * 4;
  #pragma unroll
  for (int ks = 0; ks < 4; ++ks) {
    bf16x8 a0 = ld8(uc0 + ks * 16);
    bf16x8 a1 = ld8(uc0 + 16 * 64 + ks * 16);
    #pragma unroll
    for (int j = 0; j < 4; ++j) {
      int so = (j * 16 + rr) * SPAD + ks * 16 + g * 4;
      bf16x8 bA = __builtin_bit_cast(bf16x8, *(const uint4*)(&sVA[so]));
      bf16x8 bB = __builtin_bit_cast(bf16x8, *(const uint4*)(&sVB[so]));
      accA[0][j] = __builtin_amdgcn_mfma_f32_16x16x32_bf16(a0, bA, accA[0][j], 0, 0, 0);
      accA[1][j] = __builtin_amdgcn_mfma_f32_16x16x32_bf16(a1, bA, accA[1][j], 0, 0, 0);
      accB[0][j] = __builtin_amdgcn_mfma_f32_16x16x32_bf16(a0, bB, accB[0][j], 0, 0, 0);
      accB[1][j] = __builtin_amdgcn_mfma_f32_16x16x32_bf16(a1, bB, accB[1][j], 0, 0, 0);
    }
  }
  // C/D: col = lane&15 (v), row = g*4 + reg (u)
  #pragma unroll
  for (int j = 0; j < 4; ++j) {
    int v = n0 + j * 16 + rr;
    if (v >= V_N) continue;
    float wvv = wv[v];
    #pragma unroll
    for (int i = 0; i < 2; ++i) {
      #pragma unroll
      for (int reg = 0; reg < 4; ++reg) {
        int u = m0 + i * 16 + g * 4 + reg;
        float sa = 1.0f / (1.0f + __expf(-accA[i][j][reg]));
        float sb = 1.0f / (1.0f + __expf(-accB[i][j][reg]));
        __builtin_nontemporal_store(wvv * sa + (1.0f - wvv) * sb,
                                    &out[(size_t)u * V_N + v]);
      }
    }
  }
}

extern "C" void kernel_launch(void* const* d_in, const int* in_sizes, int n_in,
                              void* d_out, int out_size, void* d_ws, size_t ws_size,
                              hipStream_t stream) {
  const float* emb_user    = (const float*)d_in[0];
  const float* emb_video   = (const float*)d_in[1];
  const float* emb_vlogger = (const float*)d_in[2];
  const float* q           = (const float*)d_in[3];
  const int*   ui_rows = (const int*)d_in[4];
  const int*   ui_cols = (const int*)d_in[5];
  const float* ui_vals = (const float*)d_in[6];
  const int*   ua_rows = (const int*)d_in[7];
  const int*   ua_cols = (const int*)d_in[8];
  const float* ua_vals = (const float*)d_in[9];
  const int*   g2_rows = (const int*)d_in[10];
  const int*   g2_cols = (const int*)d_in[11];
  const float* g2_vals = (const float*)d_in[12];
  const int*   g4_rows = (const int*)d_in[13];
  const int*   g4_cols = (const int*)d_in[14];
  const float* g4_vals = (const float*)d_in[15];
  const int*   vlist   = (const int*)d_in[16];
  const int*   users   = (const int*)d_in[17];
  int nnz_ui = in_sizes[4], nnz_ua = in_sizes[7];
  int nnz_g2 = in_sizes[10], nnz_g4 = in_sizes[13];

  float* ws = (float*)d_ws;
  float* accUI = ws;                       // 9,600,000 f
  float* accUA = ws + 9600000;             // 6,720,000 f
  u32*   curH  = (u32*)(ws + 16320000);    // 4,800,000 w
  u32*   nxtH  = (u32*)(ws + 21120000);    // 4,800,000 w
  u32*   VAH   = (u32*)(ws + 25920000);    // 3,200,000 w (50000 x 64)
  u32*   VBH   = (u32*)(ws + 29120000);    // 3,200,000 w
  u32*   UAuH  = (u32*)(ws + 32320000);    // 3,200,000 w (100000 x 32)
  u32*   UcatH = (u32*)(ws + 35520000);    //    65,536 w
  u32*   atomAH= (u32*)(ws + 35585536);    //   160,000 w
  float* wv    = ws + 35745536;            //    50,000 f
  int*   bsum  = (int*)(ws + 35795536);    //       256 w
  int*   xq    = (int*)(ws + 35795808);    //         8 w (XCD work queues)
  int*   ib    = (int*)(ws + 35800000);    // CSR area
  // VBH region doubles as batch-user scratch during propagation:
  int*   flag   = (int*)VBH;               // 100,000 w
  int*   rcount = flag + 100000;           //       1 w
  int*   rlist  = flag + 100016;           //   1,024 w

  const int nUI = U_N + V_N, nUA = U_N + A_N;
  auto nr_pad = [](int nrows) { return (size_t)((nrows + 1 + 15) & ~15); };

  // CSR build: single-pass count + XCD-queue windowed fill
  auto build_csr = [&](const int* rows, const int* cols, const float* vals,
                       int nnz, int nrows, int win, int* rp, int* pos, int2* ep) {
    hipMemsetAsync(pos, 0, (size_t)nrows * 4, stream);
    k_count<<<2048, 256, 0, stream>>>(rows, nnz, pos);
    int nb = (nrows + 1023) / 1024;
    k_bsum<<<nb, 1024, 0, stream>>>(pos, nrows, bsum);
    k_bscan<<<1, 64, 0, stream>>>(bsum, nb);
    k_bapply<<<nb, 1024, 0, stream>>>(pos, nrows, bsum, rp, pos);
    if (nrows <= win) {
      k_fill<<<2048, 256, 0, stream>>>(rows, cols, vals, nnz, pos, ep);
    } else {
      hipMemsetAsync(xq, 0, 32, stream);
      k_fillq<<<2048, 256, 0, stream>>>(rows, cols, vals, nnz, pos, ep,
                                        nrows, win, xq);
    }
  };

  // ---- UI propagation ----
  {
    size_t NR = nr_pad(nUI);
    int* rp = ib; int* pos = ib + NR; int2* ep = (int2*)(ib + 2 * NR);
    build_csr(ui_rows, ui_cols, ui_vals, nnz_ui, nUI, 16384, rp, pos, ep);
    k_concat2b<<<2048, 256, 0, stream>>>(emb_user, U_N, emb_video, V_N, curH, accUI);
    // dedupe batch users for the trimmed last layer
    hipMemsetAsync(flag, 0, (size_t)(100016) * 4, stream);
    k_mark<<<4, 256, 0, stream>>>(users, 1024, flag, rcount, rlist);
    // layers 1-2: full rows; layer 3: video rows + batch-user rows only
    k_spmm_b<<<2048, 256, 0, stream>>>(rp, ep, nUI, 0, curH, 32, nxtH, 32, 0, accUI, 0, 1);
    k_spmm_b<<<2048, 256, 0, stream>>>(rp, ep, nUI, 0, nxtH, 32, curH, 32, 0, accUI, 0, 1);
    k_spmm_b<<<2048, 256, 0, stream>>>(rp, ep, V_N, U_N, curH, 32, nullptr, 0, 0, accUI, 0, 0);
    k_spmm_b_list<<<256, 256, 0, stream>>>(rp, ep, rlist, rcount, curH, 32, accUI);
  }
  // ---- UA propagation ----
  {
    size_t NR = nr_pad(nUA);
    int* rp = ib; int* pos = ib + NR; int2* ep = (int2*)(ib + 2 * NR);
    build_csr(ua_rows, ua_cols, ua_vals, nnz_ua, nUA, 16384, rp, pos, ep);
    k_concat2b<<<2048, 256, 0, stream>>>(emb_user, U_N, emb_vlogger, A_N, curH, accUA);
    k_spmm_b<<<2048, 256, 0, stream>>>(rp, ep, nUA, 0, curH, 32, nxtH, 32, 0, accUA, 0, 1);
    k_spmm_b<<<2048, 256, 0, stream>>>(rp, ep, nUA, 0, nxtH, 32, curH, 32, 0, accUA, 0, 1);
    k_spmm_b<<<2048, 256, 0, stream>>>(rp, ep, nUA, 0, curH, 32, nullptr, 0, 0, accUA, 0, 0);
  }
  // ---- scale to means + bf16 tables ----
  k_scale_ua<<<2048, 256, 0, stream>>>(accUA, UAuH);
  k_scale_ui<<<2048, 256, 0, stream>>>(accUI, VAH);
  // ---- g4 + g2 CSRs (packed) ----
  size_t NR4 = nr_pad(V_N), NR2 = nr_pad(A_N);
  int* rp4 = ib; int* pos4 = ib + NR4; int2* ep4 = (int2*)(ib + 2 * NR4);
  int* ib2 = (int*)(ep4 + nnz_g4);
  int* rp2 = ib2; int* pos2 = ib2 + NR2; int2* ep2 = (int2*)(ib2 + 2 * NR2);
  build_csr(g4_rows, g4_cols, g4_vals, nnz_g4, V_N, 8192, rp4, pos4, ep4);
  build_csr(g2_rows, g2_cols, g2_vals, nnz_g2, A_N, 8192, rp2, pos2, ep2);
  // ---- atomAH = l2norm(spmm(g2, atom_v)) ----
  k_spmm_b<<<2048, 256, 0, stream>>>(rp2, ep2, A_N, 0, VAH, 64, atomAH, 32, 0, nullptr, 1, 1);
  // ---- non_v = l2norm(spmm(g4, non_u)) into VAH[:, 64:] ----
  k_spmm_b<<<2048, 256, 0, stream>>>(rp4, ep4, V_N, 0, UAuH, 32, VAH, 64, 32, nullptr, 1, 1);
  // ---- gathers ----
  k_gather_u<<<1024, 32, 0, stream>>>(users, accUI, accUA, UcatH);
  k_gather_vb<<<12500, 128, 0, stream>>>(vlist, atomAH, accUA, VBH);
  // ---- w ----
  k_w<<<12500, 256, 0, stream>>>(VAH, VBH, q, wv);
  // ---- rating (MFMA v2) ----
  dim3 gridR((V_N + 63) / 64, 1024 / 128);
  k_rating_mfma<<<gridR, 256, 0, stream>>>(UcatH, VAH, VBH, wv, (float*)d_out);
}

// Round 16
// 1391.187 us; speedup vs baseline: 1.4212x; 1.4212x over previous
//
#include <hip/hip_runtime.h>
#include <hip/hip_bf16.h>

#define U_N 100000
#define V_N 50000
#define A_N 5000

typedef float4 f4;
typedef unsigned int u32;
typedef __attribute__((ext_vector_type(8))) short bf16x8;
typedef __attribute__((ext_vector_type(4))) float f32x4;

__device__ inline float bflo(u32 p) { return __uint_as_float(p << 16); }
__device__ inline float bfhi(u32 p) { return __uint_as_float(p & 0xffff0000u); }
__device__ inline u32 f2bf(float f) {
  u32 u = __float_as_uint(f);
  return (u + 0x7fffu + ((u >> 16) & 1u)) >> 16;   // RTNE
}
__device__ inline u32 pack2(float lo, float hi) {
  return f2bf(lo) | (f2bf(hi) << 16);
}
__device__ inline bf16x8 ld8(const u32* p) {
  uint4 u = *(const uint4*)p;
  return __builtin_bit_cast(bf16x8, u);
}

// acc(fp32) = curH(bf16) = concat(a[na,64], b[nb,64])
__global__ void k_concat2b(const float* __restrict__ a, int na,
                           const float* __restrict__ b, int nb,
                           u32* __restrict__ curH, float* __restrict__ acc) {
  int total4 = (na + nb) * 16;
  for (int i = blockIdx.x * blockDim.x + threadIdx.x; i < total4;
       i += gridDim.x * blockDim.x) {
    int fi = i * 4;
    f4 v = (fi < na * 64) ? *(const f4*)(a + fi)
                          : *(const f4*)(b + (fi - na * 64));
    *(f4*)(acc + fi) = v;
    uint2 h; h.x = pack2(v.x, v.y); h.y = pack2(v.z, v.w);
    *(uint2*)(curH + (fi >> 1)) = h;
  }
}

// ---------------- CSR build (4 graphs, fused stages) ----------------
__global__ void k_zero4(int* p0, int n0, int* p1, int n1,
                        int* p2, int n2, int* p3, int n3) {
  int tid = blockIdx.x * blockDim.x + threadIdx.x;
  int stride = gridDim.x * blockDim.x;
  for (int i = tid; i < n0; i += stride) p0[i] = 0;
  for (int i = tid; i < n1; i += stride) p1[i] = 0;
  for (int i = tid; i < n2; i += stride) p2[i] = 0;
  for (int i = tid; i < n3; i += stride) p3[i] = 0;
}

__global__ void k_count4(const int* __restrict__ r0, int n0, int* __restrict__ c0,
                         const int* __restrict__ r1, int n1, int* __restrict__ c1,
                         const int* __restrict__ r2, int n2, int* __restrict__ c2,
                         const int* __restrict__ r3, int n3, int* __restrict__ c3,
                         int s1, int s2, int s3) {
  const int* rows; int nnz; int* cnt; int base, nb;
  int b = blockIdx.x;
  if (b < s1)      { rows = r0; nnz = n0; cnt = c0; base = 0;  nb = s1; }
  else if (b < s2) { rows = r1; nnz = n1; cnt = c1; base = s1; nb = s2 - s1; }
  else if (b < s3) { rows = r2; nnz = n2; cnt = c2; base = s2; nb = s3 - s2; }
  else             { rows = r3; nnz = n3; cnt = c3; base = s3; nb = gridDim.x - s3; }
  int tid = (b - base) * blockDim.x + threadIdx.x;
  int stride = nb * blockDim.x;
  int nq = nnz >> 2;
  for (int q = tid; q < nq; q += stride) {
    int4 r4 = *(const int4*)(rows + q * 4);
    atomicAdd(&cnt[r4.x], 1);
    atomicAdd(&cnt[r4.y], 1);
    atomicAdd(&cnt[r4.z], 1);
    atomicAdd(&cnt[r4.w], 1);
  }
  for (int i = nq * 4 + tid; i < nnz; i += stride)
    atomicAdd(&cnt[rows[i]], 1);
}

// per-graph block mapping for bsum/bapply: bases b0=0,b1,b2,b3; graph i covers
// [bi, bi+nbi); bsum is one shared buffer indexed by global block id.
__global__ void k_bsum4(const int* __restrict__ c0, int n0,
                        const int* __restrict__ c1, int n1,
                        const int* __restrict__ c2, int n2,
                        const int* __restrict__ c3, int n3,
                        int b1, int b2, int b3, int* __restrict__ bsum) {
  __shared__ int red[1024];
  const int* cnt; int n; int lb;
  int b = blockIdx.x;
  if (b < b1)      { cnt = c0; n = n0; lb = b; }
  else if (b < b2) { cnt = c1; n = n1; lb = b - b1; }
  else if (b < b3) { cnt = c2; n = n2; lb = b - b2; }
  else             { cnt = c3; n = n3; lb = b - b3; }
  int t = threadIdx.x;
  int i = lb * 1024 + t;
  red[t] = (i < n) ? cnt[i] : 0;
  __syncthreads();
  for (int off = 512; off; off >>= 1) {
    if (t < off) red[t] += red[t + off];
    __syncthreads();
  }
  if (t == 0) bsum[b] = red[0];
}

__global__ void k_bscan4(int* __restrict__ bsum, int b1, int b2, int b3, int btot) {
  if (threadIdx.x == 0) {
    int starts[5] = {0, b1, b2, b3, btot};
    for (int g = 0; g < 4; ++g) {
      int run = 0;
      for (int i = starts[g]; i < starts[g + 1]; ++i) {
        int c = bsum[i];
        bsum[i] = run;
        run += c;
      }
    }
  }
}

__global__ void k_bapply4(const int* __restrict__ c0, int n0, int* __restrict__ rp0, int* __restrict__ ps0,
                          const int* __restrict__ c1, int n1, int* __restrict__ rp1, int* __restrict__ ps1,
                          const int* __restrict__ c2, int n2, int* __restrict__ rp2, int* __restrict__ ps2,
                          const int* __restrict__ c3, int n3, int* __restrict__ rp3, int* __restrict__ ps3,
                          int b1, int b2, int b3, const int* __restrict__ bsum) {
  __shared__ int sc[1024];
  const int* cnt; int n; int* rp; int* pos; int lb;
  int b = blockIdx.x;
  if (b < b1)      { cnt = c0; n = n0; rp = rp0; pos = ps0; lb = b; }
  else if (b < b2) { cnt = c1; n = n1; rp = rp1; pos = ps1; lb = b - b1; }
  else if (b < b3) { cnt = c2; n = n2; rp = rp2; pos = ps2; lb = b - b2; }
  else             { cnt = c3; n = n3; rp = rp3; pos = ps3; lb = b - b3; }
  int t = threadIdx.x;
  int i = lb * 1024 + t;
  int c = (i < n) ? cnt[i] : 0;
  sc[t] = c;
  __syncthreads();
  #pragma unroll
  for (int off = 1; off < 1024; off <<= 1) {
    int v = (t >= off) ? sc[t - off] : 0;
    __syncthreads();
    sc[t] += v;
    __syncthreads();
  }
  int val = bsum[b] + sc[t] - c;   // exclusive
  if (i < n) {
    rp[i] = val;
    pos[i] = val;
    if (i == n - 1) rp[n] = val + c;
  }
}

// fused two-graph windowed fill (win >= nrows => single pass).
// windowed scatter stays in a per-XCD-L2-resident ep window (measured optimum).
__global__ void k_fill2(const int* __restrict__ rA, const int* __restrict__ cA,
                        const float* __restrict__ vA, int nnzA,
                        int* __restrict__ posA, int2* __restrict__ epA,
                        int nrowsA, int winA,
                        const int* __restrict__ rB, const int* __restrict__ cB,
                        const float* __restrict__ vB, int nnzB,
                        int* __restrict__ posB, int2* __restrict__ epB,
                        int nrowsB, int winB, int split) {
  const int* rows; const int* cols; const float* vals;
  int nnz, nrows, win; int* pos; int2* ep; int lb, nb;
  if (blockIdx.x < split) {
    rows = rA; cols = cA; vals = vA; nnz = nnzA; pos = posA; ep = epA;
    nrows = nrowsA; win = winA; lb = blockIdx.x; nb = split;
  } else {
    rows = rB; cols = cB; vals = vB; nnz = nnzB; pos = posB; ep = epB;
    nrows = nrowsB; win = winB; lb = blockIdx.x - split; nb = gridDim.x - split;
  }
  int tid = lb * blockDim.x + threadIdx.x;
  int stride = nb * blockDim.x;
  for (int r0 = 0; r0 < nrows; r0 += win) {
    int r1 = min(r0 + win, nrows);
    for (int i = tid; i < nnz; i += stride) {
      int r = rows[i];
      if (r >= r0 && r < r1) {
        int slot = atomicAdd(&pos[r], 1);
        ep[slot] = make_int2(cols[i], __float_as_int(vals[i]));
      }
    }
  }
}

// dedupe batch users -> rlist/rcount (flag must be zeroed)
__global__ void k_mark(const int* __restrict__ users, int nb,
                       int* __restrict__ flag, int* __restrict__ rcount,
                       int* __restrict__ rlist) {
  int b = blockIdx.x * blockDim.x + threadIdx.x;
  if (b < nb) {
    int u = users[b];
    if (atomicExch(&flag[u], 1) == 0) {
      int m = atomicAdd(rcount, 1);
      rlist[m] = u;
    }
  }
}

// ---------------- bf16 gather SpMM row routine ----------------
__device__ __forceinline__ void spmm_row(
    int row, const int* __restrict__ rp, const int2* __restrict__ ep,
    const u32* __restrict__ inH, int instrU,
    u32* __restrict__ outH, int ostrU, int ocolU,
    float* __restrict__ acc, int l2n, int wout, int lane, int eg, int du) {
  int e0 = rp[row], e1 = rp[row + 1];
  float s[8] = {0.f, 0.f, 0.f, 0.f, 0.f, 0.f, 0.f, 0.f};
  int e = e0 + eg;
  for (; e + 8 < e1; e += 16) {
    int2 ed0 = ep[e];
    int2 ed1 = ep[e + 8];
    float v0 = __int_as_float(ed0.y), v1 = __int_as_float(ed1.y);
    uint4 x0 = *(const uint4*)(inH + (size_t)ed0.x * instrU + du);
    uint4 x1 = *(const uint4*)(inH + (size_t)ed1.x * instrU + du);
    s[0] = fmaf(v0, bflo(x0.x), s[0]); s[1] = fmaf(v0, bfhi(x0.x), s[1]);
    s[2] = fmaf(v0, bflo(x0.y), s[2]); s[3] = fmaf(v0, bfhi(x0.y), s[3]);
    s[4] = fmaf(v0, bflo(x0.z), s[4]); s[5] = fmaf(v0, bfhi(x0.z), s[5]);
    s[6] = fmaf(v0, bflo(x0.w), s[6]); s[7] = fmaf(v0, bfhi(x0.w), s[7]);
    s[0] = fmaf(v1, bflo(x1.x), s[0]); s[1] = fmaf(v1, bfhi(x1.x), s[1]);
    s[2] = fmaf(v1, bflo(x1.y), s[2]); s[3] = fmaf(v1, bfhi(x1.y), s[3]);
    s[4] = fmaf(v1, bflo(x1.z), s[4]); s[5] = fmaf(v1, bfhi(x1.z), s[5]);
    s[6] = fmaf(v1, bflo(x1.w), s[6]); s[7] = fmaf(v1, bfhi(x1.w), s[7]);
  }
  if (e < e1) {
    int2 ed0 = ep[e];
    float v0 = __int_as_float(ed0.y);
    uint4 x0 = *(const uint4*)(inH + (size_t)ed0.x * instrU + du);
    s[0] = fmaf(v0, bflo(x0.x), s[0]); s[1] = fmaf(v0, bfhi(x0.x), s[1]);
    s[2] = fmaf(v0, bflo(x0.y), s[2]); s[3] = fmaf(v0, bfhi(x0.y), s[3]);
    s[4] = fmaf(v0, bflo(x0.z), s[4]); s[5] = fmaf(v0, bfhi(x0.z), s[5]);
    s[6] = fmaf(v0, bflo(x0.w), s[6]); s[7] = fmaf(v0, bfhi(x0.w), s[7]);
  }
  #pragma unroll
  for (int j = 0; j < 8; ++j) {
    s[j] += __shfl_xor(s[j], 8);
    s[j] += __shfl_xor(s[j], 16);
    s[j] += __shfl_xor(s[j], 32);
  }
  if (l2n) {
    float ss = 0.f;
    #pragma unroll
    for (int j = 0; j < 8; ++j) ss = fmaf(s[j], s[j], ss);
    ss += __shfl_xor(ss, 1);
    ss += __shfl_xor(ss, 2);
    ss += __shfl_xor(ss, 4);
    float inv = 1.0f / fmaxf(sqrtf(ss), 1e-12f);
    #pragma unroll
    for (int j = 0; j < 8; ++j) s[j] *= inv;
  }
  if (eg == 0) {
    if (wout) {
      uint4 o;
      o.x = pack2(s[0], s[1]); o.y = pack2(s[2], s[3]);
      o.z = pack2(s[4], s[5]); o.w = pack2(s[6], s[7]);
      *(uint4*)(outH + (size_t)row * ostrU + ocolU + du) = o;
    }
    if (acc) {
      float* ap = acc + (size_t)row * 64 + (lane & 7) * 8;
      f4 a0 = *(f4*)ap, a1 = *(f4*)(ap + 4);
      a0.x += s[0]; a0.y += s[1]; a0.z += s[2]; a0.w += s[3];
      a1.x += s[4]; a1.y += s[5]; a1.z += s[6]; a1.w += s[7];
      *(f4*)ap = a0; *(f4*)(ap + 4) = a1;
    }
  }
}

__global__ void k_spmm_b(const int* __restrict__ rp, const int2* __restrict__ ep,
                         int nrows, int rbase,
                         const u32* __restrict__ inH, int instrU,
                         u32* __restrict__ outH, int ostrU, int ocolU,
                         float* __restrict__ acc, int l2n, int wout) {
  int lane = threadIdx.x & 63;
  int w = (blockIdx.x * blockDim.x + threadIdx.x) >> 6;
  int nw = (gridDim.x * blockDim.x) >> 6;
  int eg = lane >> 3;
  int du = (lane & 7) * 4;
  for (int r = w; r < nrows; r += nw)
    spmm_row(rbase + r, rp, ep, inH, instrU, outH, ostrU, ocolU, acc, l2n, wout,
             lane, eg, du);
}

// fused two-graph SpMM (both l2norm+wout), block-partitioned
__global__ void k_spmm2(const int* __restrict__ rpA, const int2* __restrict__ epA,
                        int nrowsA, const u32* __restrict__ inA, int instrA,
                        u32* __restrict__ outA, int ostrA, int ocolA,
                        const int* __restrict__ rpB, const int2* __restrict__ epB,
                        int nrowsB, const u32* __restrict__ inB, int instrB,
                        u32* __restrict__ outB, int ostrB, int ocolB,
                        int split) {
  const int* rp; const int2* ep; int nrows; const u32* inH; int instrU;
  u32* outH; int ostrU, ocolU; int lb, nbk;
  if (blockIdx.x < split) {
    rp = rpA; ep = epA; nrows = nrowsA; inH = inA; instrU = instrA;
    outH = outA; ostrU = ostrA; ocolU = ocolA; lb = blockIdx.x; nbk = split;
  } else {
    rp = rpB; ep = epB; nrows = nrowsB; inH = inB; instrU = instrB;
    outH = outB; ostrU = ostrB; ocolU = ocolB;
    lb = blockIdx.x - split; nbk = gridDim.x - split;
  }
  int lane = threadIdx.x & 63;
  int w = (lb * blockDim.x + threadIdx.x) >> 6;
  int nw = (nbk * blockDim.x) >> 6;
  int eg = lane >> 3;
  int du = (lane & 7) * 4;
  for (int r = w; r < nrows; r += nw)
    spmm_row(r, rp, ep, inH, instrU, outH, ostrU, ocolU, nullptr, 1, 1,
             lane, eg, du);
}

// acc-only SpMM over an explicit row list (deduped)
__global__ void k_spmm_b_list(const int* __restrict__ rp, const int2* __restrict__ ep,
                              const int* __restrict__ rlist, const int* __restrict__ rcount,
                              const u32* __restrict__ inH, int instrU,
                              float* __restrict__ acc) {
  int lane = threadIdx.x & 63;
  int w = (blockIdx.x * blockDim.x + threadIdx.x) >> 6;
  int nw = (gridDim.x * blockDim.x) >> 6;
  int eg = lane >> 3;
  int du = (lane & 7) * 4;
  int m = *rcount;
  for (int r = w; r < m; r += nw)
    spmm_row(rlist[r], rp, ep, inH, instrU, nullptr, 0, 0, acc, 0, 0,
             lane, eg, du);
}

// fused scales: accUI *= .25 (video rows -> VAH[:, :64]); accUA *= .25
// (user rows -> UAuH). Block-partitioned.
__global__ void k_scale2(float* __restrict__ accUI, u32* __restrict__ VAH,
                         float* __restrict__ accUA, u32* __restrict__ UAuH,
                         int split) {
  if (blockIdx.x < split) {
    int total4 = (U_N + V_N) * 16;
    int tid = blockIdx.x * blockDim.x + threadIdx.x;
    int stride = split * blockDim.x;
    for (int i = tid; i < total4; i += stride) {
      int fi = i * 4;
      f4 v = *(f4*)(accUI + fi);
      v.x *= 0.25f; v.y *= 0.25f; v.z *= 0.25f; v.w *= 0.25f;
      *(f4*)(accUI + fi) = v;
      if (fi >= U_N * 64) {
        int rem = fi - U_N * 64;
        int row = rem >> 6, col = rem & 63;
        uint2 h; h.x = pack2(v.x, v.y); h.y = pack2(v.z, v.w);
        *(uint2*)(VAH + (size_t)row * 64 + (col >> 1)) = h;
      }
    }
  } else {
    int total4 = (U_N + A_N) * 16;
    int tid = (blockIdx.x - split) * blockDim.x + threadIdx.x;
    int stride = (gridDim.x - split) * blockDim.x;
    for (int i = tid; i < total4; i += stride) {
      int fi = i * 4;
      f4 v = *(f4*)(accUA + fi);
      v.x *= 0.25f; v.y *= 0.25f; v.z *= 0.25f; v.w *= 0.25f;
      *(f4*)(accUA + fi) = v;
      if (fi < U_N * 64) {
        uint2 h; h.x = pack2(v.x, v.y); h.y = pack2(v.z, v.w);
        *(uint2*)(UAuH + (fi >> 1)) = h;
      }
    }
  }
}

// UcatH[b] = bf16([atom_u[users[b]] | non_u[users[b]]]); 32 threads/block
__global__ void k_gather_u(const int* __restrict__ users,
                           const float* __restrict__ accUI,
                           const float* __restrict__ accUA,
                           u32* __restrict__ UcatH) {
  int b = blockIdx.x;
  int t = threadIdx.x;
  int u = users[b];
  UcatH[b * 64 + t] = pack2(accUI[(size_t)u * 64 + 2 * t], accUI[(size_t)u * 64 + 2 * t + 1]);
  UcatH[b * 64 + 32 + t] = pack2(accUA[(size_t)u * 64 + 2 * t], accUA[(size_t)u * 64 + 2 * t + 1]);
}

// VBH[v] = [atomAH[vl[v]] | bf16(non_a[vl[v]])]; 128 threads = 4 videos
__global__ void k_gather_vb(const int* __restrict__ vlist,
                            const u32* __restrict__ atomAH,
                            const float* __restrict__ accUA,
                            u32* __restrict__ VBH) {
  int v = blockIdx.x * 4 + (threadIdx.x >> 5);
  int t = threadIdx.x & 31;
  int a = vlist[v];
  VBH[(size_t)v * 64 + t] = atomAH[(size_t)a * 32 + t];
  VBH[(size_t)v * 64 + 32 + t] =
      pack2(accUA[(size_t)(U_N + a) * 64 + 2 * t], accUA[(size_t)(U_N + a) * 64 + 2 * t + 1]);
}

// w[v] = sigmoid( dot( ((atom_v+non_v)/2) @ q , (vl_a+vl_n)/2 ) )
__global__ void k_w(const u32* __restrict__ VAH, const u32* __restrict__ VBH,
                    const float* __restrict__ q, float* __restrict__ wv) {
  __shared__ float qs[64 * 64];
  for (int i = threadIdx.x; i < 4096; i += blockDim.x) qs[i] = q[i];
  __syncthreads();
  int lane = threadIdx.x & 63;
  int v = blockIdx.x * 4 + (threadIdx.x >> 6);
  if (v >= V_N) return;
  int half = lane & 1;
  u32 pa0 = VAH[(size_t)v * 64 + (lane >> 1)];
  u32 pa1 = VAH[(size_t)v * 64 + 32 + (lane >> 1)];
  u32 pb0 = VBH[(size_t)v * 64 + (lane >> 1)];
  u32 pb1 = VBH[(size_t)v * 64 + 32 + (lane >> 1)];
  float vid = 0.5f * ((half ? bfhi(pa0) : bflo(pa0)) + (half ? bfhi(pa1) : bflo(pa1)));
  float vlog = 0.5f * ((half ? bfhi(pb0) : bflo(pb0)) + (half ? bfhi(pb1) : bflo(pb1)));
  float s = 0.0f;
  for (int d = 0; d < 64; ++d)
    s = fmaf(__shfl(vid, d, 64), qs[d * 64 + lane], s);
  float t = s * vlog;
  #pragma unroll
  for (int off = 32; off; off >>= 1) t += __shfl_xor(t, off, 64);
  if (lane == 0) wv[v] = 1.0f / (1.0f + __expf(-t));
}

// MFMA rating v2: block = 4 waves, each wave 32u x 64v; VA/VB tile in LDS.
#define SPAD 68
__global__ __launch_bounds__(256) void k_rating_mfma(
    const u32* __restrict__ UcatH, const u32* __restrict__ VAH,
    const u32* __restrict__ VBH, const float* __restrict__ wv,
    float* __restrict__ out) {
  __shared__ u32 sVA[64 * SPAD];
  __shared__ u32 sVB[64 * SPAD];
  int t = threadIdx.x;
  int n0 = blockIdx.x * 64;
  for (int i = t; i < 1024; i += 256) {
    int row = i >> 4, c4 = (i & 15) * 4;
    int v = n0 + row;
    uint4 a = make_uint4(0, 0, 0, 0), b = make_uint4(0, 0, 0, 0);
    if (v < V_N) {
      a = *(const uint4*)(VAH + (size_t)v * 64 + c4);
      b = *(const uint4*)(VBH + (size_t)v * 64 + c4);
    }
    *(uint4*)(&sVA[row * SPAD + c4]) = a;
    *(uint4*)(&sVB[row * SPAD + c4]) = b;
  }
  __syncthreads();
  int lane = t & 63, wave = t >> 6;
  int m0 = (blockIdx.y * 4 + wave) * 32;
  int rr = lane & 15, g = lane >> 4;
  f32x4 accA[2][4], accB[2][4];
  #pragma unroll
  for (int i = 0; i < 2; ++i)
    #pragma unroll
    for (int j = 0; j < 4; ++j) {
      accA[i][j] = (f32x4){0.f, 0.f, 0.f, 0.f};
      accB[i][j] = (f32x4){0.f, 0.f, 0.f, 0.f};
    }
  const u32* uc0 = UcatH + (size_t)(m0 + rr) * 64 + g * 4;
  #pragma unroll
  for (int ks = 0; ks < 4; ++ks) {
    bf16x8 a0 = ld8(uc0 + ks * 16);
    bf16x8 a1 = ld8(uc0 + 16 * 64 + ks * 16);
    #pragma unroll
    for (int j = 0; j < 4; ++j) {
      int so = (j * 16 + rr) * SPAD + ks * 16 + g * 4;
      bf16x8 bA = __builtin_bit_cast(bf16x8, *(const uint4*)(&sVA[so]));
      bf16x8 bB = __builtin_bit_cast(bf16x8, *(const uint4*)(&sVB[so]));
      accA[0][j] = __builtin_amdgcn_mfma_f32_16x16x32_bf16(a0, bA, accA[0][j], 0, 0, 0);
      accA[1][j] = __builtin_amdgcn_mfma_f32_16x16x32_bf16(a1, bA, accA[1][j], 0, 0, 0);
      accB[0][j] = __builtin_amdgcn_mfma_f32_16x16x32_bf16(a0, bB, accB[0][j], 0, 0, 0);
      accB[1][j] = __builtin_amdgcn_mfma_f32_16x16x32_bf16(a1, bB, accB[1][j], 0, 0, 0);
    }
  }
  // C/D: col = lane&15 (v), row = g*4 + reg (u)
  #pragma unroll
  for (int j = 0; j < 4; ++j) {
    int v = n0 + j * 16 + rr;
    if (v >= V_N) continue;
    float wvv = wv[v];
    #pragma unroll
    for (int i = 0; i < 2; ++i) {
      #pragma unroll
      for (int reg = 0; reg < 4; ++reg) {
        int u = m0 + i * 16 + g * 4 + reg;
        float sa = 1.0f / (1.0f + __expf(-accA[i][j][reg]));
        float sb = 1.0f / (1.0f + __expf(-accB[i][j][reg]));
        __builtin_nontemporal_store(wvv * sa + (1.0f - wvv) * sb,
                                    &out[(size_t)u * V_N + v]);
      }
    }
  }
}

extern "C" void kernel_launch(void* const* d_in, const int* in_sizes, int n_in,
                              void* d_out, int out_size, void* d_ws, size_t ws_size,
                              hipStream_t stream) {
  const float* emb_user    = (const float*)d_in[0];
  const float* emb_video   = (const float*)d_in[1];
  const float* emb_vlogger = (const float*)d_in[2];
  const float* q           = (const float*)d_in[3];
  const int*   ui_rows = (const int*)d_in[4];
  const int*   ui_cols = (const int*)d_in[5];
  const float* ui_vals = (const float*)d_in[6];
  const int*   ua_rows = (const int*)d_in[7];
  const int*   ua_cols = (const int*)d_in[8];
  const float* ua_vals = (const float*)d_in[9];
  const int*   g2_rows = (const int*)d_in[10];
  const int*   g2_cols = (const int*)d_in[11];
  const float* g2_vals = (const float*)d_in[12];
  const int*   g4_rows = (const int*)d_in[13];
  const int*   g4_cols = (const int*)d_in[14];
  const float* g4_vals = (const float*)d_in[15];
  const int*   vlist   = (const int*)d_in[16];
  const int*   users   = (const int*)d_in[17];
  int nnz_ui = in_sizes[4], nnz_ua = in_sizes[7];
  int nnz_g2 = in_sizes[10], nnz_g4 = in_sizes[13];

  float* ws = (float*)d_ws;
  // fixed buffers
  float* accUI = ws;                        // [0, 9.6M)
  float* accUA = ws + 9600000;              // [9.6M, 16.32M)
  u32*   curH  = (u32*)(ws + 16320000);     // [16.32M, 21.12M)
  u32*   nxtH  = (u32*)(ws + 21120000);     // [21.12M, 25.92M)
  u32*   VAH   = (u32*)(ws + 25920000);     // [25.92M, 29.12M)
  u32*   VBH   = (u32*)(ws + 29120000);     // [29.12M, 32.32M)
  u32*   UAuH  = (u32*)(ws + 32320000);     // [32.32M, 35.52M)
  u32*   UcatH = (u32*)(ws + 35520000);
  u32*   atomAH= (u32*)(ws + 35585536);
  float* wv    = ws + 35745536;
  int*   bsum  = (int*)(ws + 35795536);     // 4464 words avail (need 304)
  // UI CSR (area A)
  int*   rpUI  = (int*)(ws + 35800000);     // 150,016
  int*   posUI = rpUI + 150016;
  int2*  epUI  = (int2*)(rpUI + 300032);    // 4M entries -> end 44,100,032 w
  // area B (VBH+UAuH region; dead during propagation)
  int*   rp4   = (int*)VBH;                 // 50,016
  int*   pos4  = rp4 + 50016;               // 50,016
  int*   rp2   = rp4 + 100032;              // 5,008
  int*   pos2  = rp4 + 105040;              // 5,008
  int*   rpUA  = rp4 + 110048;              // 105,008
  int*   posUA = rpUA + 105008;             // 105,008
  int2*  epUA  = (int2*)(rpUA + 210016);    // 2M entries (ends 33,440,064 w)
  // g4/g2 edges live in dead curH/nxtH after propagation
  int2*  ep4   = (int2*)curH;               // 2M entries -> 4M w (end 20.32M)
  int2*  ep2   = (int2*)(ws + 20320000);    // 200K entries (end 20.72M)
  // batch-user scratch in atomAH region (dead until g2 SpMM)
  int*   flag   = (int*)atomAH;             // 100,000
  int*   rcount = flag + 100000;
  int*   rlist  = flag + 100016;

  const int nUI = U_N + V_N, nUA = U_N + A_N;

  // ---- build all 4 CSR skeletons up-front (fused stages) ----
  k_zero4<<<512, 256, 0, stream>>>(posUI, nUI, posUA, nUA, pos4, V_N, pos2, A_N);
  k_count4<<<2048, 256, 0, stream>>>(ui_rows, nnz_ui, posUI,
                                     ua_rows, nnz_ua, posUA,
                                     g4_rows, nnz_g4, pos4,
                                     g2_rows, nnz_g2, pos2,
                                     1000, 1500, 2000);
  int nbUI = (nUI + 1023) / 1024, nbUA = (nUA + 1023) / 1024;
  int nb4 = (V_N + 1023) / 1024, nb2 = (A_N + 1023) / 1024;
  int b1 = nbUI, b2 = b1 + nbUA, b3 = b2 + nb4, btot = b3 + nb2;
  k_bsum4<<<btot, 1024, 0, stream>>>(posUI, nUI, posUA, nUA, pos4, V_N, pos2, A_N,
                                     b1, b2, b3, bsum);
  k_bscan4<<<1, 64, 0, stream>>>(bsum, b1, b2, b3, btot);
  k_bapply4<<<btot, 1024, 0, stream>>>(posUI, nUI, rpUI, posUI,
                                       posUA, nUA, rpUA, posUA,
                                       pos4, V_N, rp4, pos4,
                                       pos2, A_N, rp2, pos2,
                                       b1, b2, b3, bsum);
  // fused UI+UA fill (windowed; win=16K rows = per-XCD-L2-resident ep window)
  k_fill2<<<2048, 256, 0, stream>>>(ui_rows, ui_cols, ui_vals, nnz_ui, posUI, epUI,
                                    nUI, 16384,
                                    ua_rows, ua_cols, ua_vals, nnz_ua, posUA, epUA,
                                    nUA, 16384, 1536);
  // batch-user dedupe
  hipMemsetAsync(flag, 0, (size_t)100016 * 4, stream);
  k_mark<<<4, 256, 0, stream>>>(users, 1024, flag, rcount, rlist);

  // ---- UI propagation ----
  k_concat2b<<<2048, 256, 0, stream>>>(emb_user, U_N, emb_video, V_N, curH, accUI);
  k_spmm_b<<<2048, 256, 0, stream>>>(rpUI, epUI, nUI, 0, curH, 32, nxtH, 32, 0, accUI, 0, 1);
  k_spmm_b<<<2048, 256, 0, stream>>>(rpUI, epUI, nUI, 0, nxtH, 32, curH, 32, 0, accUI, 0, 1);
  k_spmm_b<<<2048, 256, 0, stream>>>(rpUI, epUI, V_N, U_N, curH, 32, nullptr, 0, 0, accUI, 0, 0);
  k_spmm_b_list<<<256, 256, 0, stream>>>(rpUI, epUI, rlist, rcount, curH, 32, accUI);

  // ---- UA propagation ----
  k_concat2b<<<2048, 256, 0, stream>>>(emb_user, U_N, emb_vlogger, A_N, curH, accUA);
  k_spmm_b<<<2048, 256, 0, stream>>>(rpUA, epUA, nUA, 0, curH, 32, nxtH, 32, 0, accUA, 0, 1);
  k_spmm_b<<<2048, 256, 0, stream>>>(rpUA, epUA, nUA, 0, nxtH, 32, curH, 32, 0, accUA, 0, 1);
  k_spmm_b<<<2048, 256, 0, stream>>>(rpUA, epUA, nUA, 0, curH, 32, nullptr, 0, 0, accUA, 0, 0);

  // ---- g4 + g2 fills (curH/nxtH now dead) ----
  k_fill2<<<2048, 256, 0, stream>>>(g4_rows, g4_cols, g4_vals, nnz_g4, pos4, ep4,
                                    V_N, 8192,
                                    g2_rows, g2_cols, g2_vals, nnz_g2, pos2, ep2,
                                    A_N, 1 << 20, 1920);
  // ---- fused scales (means + bf16 tables) ----
  k_scale2<<<2048, 256, 0, stream>>>(accUI, VAH, accUA, UAuH, 1200);
  // ---- fused g2 SpMM (atom_a) + g4 SpMM (non_v), both l2norm ----
  k_spmm2<<<2048, 256, 0, stream>>>(rp2, ep2, A_N, VAH, 64, atomAH, 32, 0,
                                    rp4, ep4, V_N, UAuH, 32, VAH, 64, 32, 192);
  // ---- gathers + w + rating ----
  k_gather_u<<<1024, 32, 0, stream>>>(users, accUI, accUA, UcatH);
  k_gather_vb<<<12500, 128, 0, stream>>>(vlist, atomAH, accUA, VBH);
  k_w<<<12500, 256, 0, stream>>>(VAH, VBH, q, wv);
  dim3 gridR((V_N + 63) / 64, 1024 / 128);
  k_rating_mfma<<<gridR, 256, 0, stream>>>(UcatH, VAH, VBH, wv, (float*)d_out);
}